// Round 3
// baseline (265.076 us; speedup 1.0000x reference)
//
#include <hip/hip_runtime.h>
#include <hip/hip_bf16.h>
#include <stdint.h>

// Problem constants: N=4096, K=2, E=8, D=1024, H=1024
#define N_TOK   4096
#define TOPK    2
#define N_EXP   8
#define D_MODEL 1024
#define H_DIM   1024
#define NK      (N_TOK * TOPK)   // 8192 token-copies
#define MAX_TILES 72             // sum over experts of ceil(gs/128) <= 64+7

typedef __attribute__((ext_vector_type(8))) short bf16x8;  // 8 bf16 (4 VGPRs)
typedef __attribute__((ext_vector_type(4))) float f32x4;   // MFMA accumulator
typedef __attribute__((ext_vector_type(4))) unsigned int uint32x4;
typedef __attribute__((ext_vector_type(2))) unsigned int uint32x2;
typedef unsigned short bfbits;

__device__ inline bfbits f2bf_bits(float f) {
  union { float f; unsigned int u; } v; v.f = f;
  unsigned int r = v.u + 0x7FFFu + ((v.u >> 16) & 1u);  // RNE
  return (bfbits)(r >> 16);
}
__device__ inline float bf2f(unsigned short u) {
  union { unsigned int u; float f; } v; v.u = ((unsigned int)u) << 16;
  return v.f;
}

// async global->LDS, 16B/lane; LDS dest = wave-uniform base + lane*16
__device__ inline void glds16(const bfbits* g, bfbits* l) {
  __builtin_amdgcn_global_load_lds(
      (const __attribute__((address_space(1))) void*)g,
      (__attribute__((address_space(3))) void*)l, 16, 0, 0);
}

// ---- fused pre-pass ----
// z == 0       : (block 0,0 only) meta + bucket sort  (dispatched FIRST -> hides under bulk)
// 1 <= z <= 24 : transpose+convert weight matrix z-1 (w1:0-7, w3:8-15, w2:16-23)
//                128(rows) x 64(cols) tile per block, reg-staged, swizzled LDS
// 25 <= z <= 32: convert x -> bf16 (4 float4/thread) + zero-fill out (4 float4/thread)
// meta: [0..8] offs (excl scan), [17] ntiles, [18..89] tile_expert, [90..161] tile_row0
__global__ __launch_bounds__(256, 4) void prepass_kernel(
    const float* __restrict__ x, const int* __restrict__ eidx,
    const int* __restrict__ bspe,
    const float* __restrict__ w1, const float* __restrict__ w2,
    const float* __restrict__ w3,
    bfbits* __restrict__ w1t, bfbits* __restrict__ w2t,
    bfbits* __restrict__ w3t, bfbits* __restrict__ xb,
    int* __restrict__ meta, int* __restrict__ row_src,
    int* __restrict__ pos_of, float4* __restrict__ outz) {
  int z = blockIdx.z;
  int tid = threadIdx.x;

  if (z >= 1 && z <= 24) {
    // ---------- weight transpose + fp32->bf16 ----------
    int zz = z - 1;
    const size_t MAT = (size_t)1024 * 1024;
    const float* src; bfbits* dst;
    if (zz < 8)       { src = w1 + (size_t)zz * MAT;        dst = w1t + (size_t)zz * MAT; }
    else if (zz < 16) { src = w3 + (size_t)(zz - 8) * MAT;  dst = w3t + (size_t)(zz - 8) * MAT; }
    else              { src = w2 + (size_t)(zz - 16) * MAT; dst = w2t + (size_t)(zz - 16) * MAT; }

    // LDS tile stored TRANSPOSED: logical T[a][b], a = src col (0..63),
    // b = src row (0..127). Row pitch 264 B (132 shorts): 8B-aligned rows.
    // Bank swizzle: inner byte ^= ((a>>4)&3)<<3 (stays within the 264B row,
    // bijective; makes both packed writes and vector reads ~2-way).
    __shared__ __align__(16) bfbits Ts[64 * 132];   // 16.5 KB
    char* tsb = (char*)Ts;

    int r0 = blockIdx.y * 128, c0 = blockIdx.x * 64;
    int k = tid & 15, qw = tid >> 4;
    int c = k * 4;

    // phase 1: 8 independent float4 loads into regs (deep VMEM queue)
    float4 v0[4], v1[4];
#pragma unroll
    for (int it = 0; it < 4; it++) {
      int r = it * 32 + qw * 2;
      v0[it] = *(const float4*)&src[(size_t)(r0 + r) * 1024 + c0 + c];
      v1[it] = *(const float4*)&src[(size_t)(r0 + r + 1) * 1024 + c0 + c];
    }
    // phase 2: convert + packed ushort2 writes at transposed coords
#pragma unroll
    for (int it = 0; it < 4; it++) {
      int r = it * 32 + qw * 2;
      const float* a0 = (const float*)&v0[it];
      const float* a1 = (const float*)&v1[it];
#pragma unroll
      for (int j = 0; j < 4; j++) {
        int a = c + j;
        int xo = ((a >> 4) & 3) << 3;
        unsigned int pk = (unsigned int)f2bf_bits(a0[j]) |
                          ((unsigned int)f2bf_bits(a1[j]) << 16);
        *(unsigned int*)(tsb + a * 264 + ((r * 2) ^ xo)) = pk;
      }
    }
    __syncthreads();
    // phase 3: vector 8B LDS reads along output rows, 16B global stores
    int g = tid >> 3, m = tid & 7;
#pragma unroll
    for (int it2 = 0; it2 < 2; it2++) {
      int o = it2 * 32 + g;                 // output row = source col
      int base = o * 264;
      int xo = ((o >> 4) & 3) << 3;
      uint32x2 p0 = *(const uint32x2*)(tsb + base + ((m * 32 +  0) ^ xo));
      uint32x2 p1 = *(const uint32x2*)(tsb + base + ((m * 32 +  8) ^ xo));
      uint32x2 p2 = *(const uint32x2*)(tsb + base + ((m * 32 + 16) ^ xo));
      uint32x2 p3 = *(const uint32x2*)(tsb + base + ((m * 32 + 24) ^ xo));
      size_t ob = (size_t)(c0 + o) * 1024 + r0 + m * 16;
      uint32x4 s0; s0.x = p0.x; s0.y = p0.y; s0.z = p1.x; s0.w = p1.y;
      uint32x4 s1; s1.x = p2.x; s1.y = p2.y; s1.z = p3.x; s1.w = p3.y;
      *(uint32x4*)&dst[ob] = s0;
      *(uint32x4*)&dst[ob + 8] = s1;
    }
  } else if (z >= 25) {
    // ---------- x fp32 -> bf16 + zero-fill out ----------
    int idx = (z - 25) * 128 + blockIdx.y * 16 + blockIdx.x;  // 0..1023
    const float4* xv = (const float4*)x;
    ushort4* xo = (ushort4*)xb;
    const float4 z4 = {0.f, 0.f, 0.f, 0.f};
#pragma unroll
    for (int q = 0; q < 4; q++) {
      int fi = idx * 1024 + q * 256 + tid;
      float4 v = xv[fi];
      ushort4 o;
      o.x = f2bf_bits(v.x); o.y = f2bf_bits(v.y);
      o.z = f2bf_bits(v.z); o.w = f2bf_bits(v.w);
      xo[fi] = o;
      outz[fi] = z4;   // out is (N_TOK*D) floats = same float4 index space
    }
  } else {
    // ---------- z == 0: meta + bucket sort ----------
    if (blockIdx.x != 0 || blockIdx.y != 0) return;
    __shared__ int sm[162];
    __shared__ int scnt[N_EXP];
    if (tid == 0) {
      int acc = 0, nt = 0;
      for (int e = 0; e < N_EXP; e++) {
        sm[e] = acc;
        int g = bspe[e];
        for (int tt = 0; tt * 128 < g; tt++) {
          sm[18 + nt] = e;
          sm[90 + nt] = acc + tt * 128;
          nt++;
        }
        acc += g;
      }
      sm[8] = acc;
      sm[17] = nt;
      for (int i = nt; i < MAX_TILES; i++) { sm[18 + i] = 0; sm[90 + i] = 0; }
    }
    if (tid < N_EXP) scnt[tid] = 0;
    __syncthreads();
    // prefetch all expert indices first (8 int4 loads in flight), then bucket
    int4 eb[8];
#pragma unroll
    for (int q = 0; q < 8; q++) eb[q] = ((const int4*)eidx)[q * 256 + tid];
#pragma unroll
    for (int q = 0; q < 8; q++) {
      int ii = (q * 256 + tid) * 4;
      const int* ev = (const int*)&eb[q];
#pragma unroll
      for (int j = 0; j < 4; j++) {
        int e = ev[j];
        int p = sm[e] + atomicAdd(&scnt[e], 1);
        row_src[p] = ii + j;
        pos_of[ii + j] = p;
      }
    }
    if (tid < 162) meta[tid] = sm[tid];
  }
}

// ---- grouped GEMM 1: h = silu(x@w1) * (x@w3), bf16 out (NK,H) ----
// 128x64 tile, BK=64, 4 waves of 64x32, dual acc.
// 2-phase double-buffered LDS (64 KB): prefetch(kk+1) issued BEFORE compute(kk),
// ONE __syncthreads per K-step -> HBM latency hides under MFMA.
__global__ __launch_bounds__(256, 2) void gemm_swiglu_kernel(
    const bfbits* __restrict__ xb, const bfbits* __restrict__ w1t,
    const bfbits* __restrict__ w3t, const int* __restrict__ row_src,
    const int* __restrict__ meta, bfbits* __restrict__ hb) {
  int nt = meta[17];
  int bt = blockIdx.y;
  if (bt >= nt) return;
  int e = meta[18 + bt];
  int row0 = meta[90 + bt];
  int rows_end = meta[e + 1];
  int n0 = blockIdx.x * 64;

  // per half (16384 bfbits): A [0,8192), B1 [8192,12288), B3 [12288,16384)
  __shared__ __align__(16) bfbits smbuf[2][16384];   // 64 KB

  int tid = threadIdx.x, lane = tid & 63, wv = tid >> 6;
  int r8 = lane >> 3, jl = lane & 7;
  int jg = jl ^ r8;   // swizzled global 16B chunk for this lane

  // 32 staging segments of 8 rows each: [0..15]=A, [16..23]=B1, [24..31]=B3
  const bfbits* gp[8]; int lpo[8];
  for (int j = 0; j < 8; j++) {
    int s = wv * 8 + j;
    if (s < 16) {
      int tok = row_src[row0 + s * 8 + r8] >> 1;  // TOPK=2; rows>=rows_end read valid junk, discarded
      gp[j] = xb + (size_t)tok * D_MODEL + jg * 8;
      lpo[j] = s * 512;
    } else if (s < 24) {
      int b = s - 16;
      gp[j] = w1t + ((size_t)e * H_DIM + n0 + b * 8 + r8) * D_MODEL + jg * 8;
      lpo[j] = 8192 + b * 512;
    } else {
      int b = s - 24;
      gp[j] = w3t + ((size_t)e * H_DIM + n0 + b * 8 + r8) * D_MODEL + jg * 8;
      lpo[j] = 12288 + b * 512;
    }
  }

  const f32x4 fzero = {0.f, 0.f, 0.f, 0.f};
  f32x4 accg[4][2], accu[4][2];
  for (int i = 0; i < 4; i++)
    for (int j = 0; j < 2; j++) { accg[i][j] = fzero; accu[i][j] = fzero; }

  int mw = (wv & 1) * 64, nwv = (wv >> 1) * 32;
  int qd = lane >> 4, lr = lane & 15, lr7 = lr & 7;

  // prologue: stage K-tile 0 into half 0
  for (int j = 0; j < 8; j++) glds16(gp[j], &smbuf[0][0] + lpo[j]);
  __syncthreads();

  for (int kk = 0; kk < D_MODEL / 64; kk++) {
    int cur = kk & 1;
    if (kk < D_MODEL / 64 - 1) {
      int ko = (kk + 1) * 64;
      bfbits* nx = &smbuf[cur ^ 1][0];
      for (int j = 0; j < 8; j++) glds16(gp[j] + ko, nx + lpo[j]);
    }
    const bfbits* As  = &smbuf[cur][0];
    const bfbits* B1s = As + 8192;
    const bfbits* B3s = As + 12288;
    for (int ks = 0; ks < 2; ks++) {
      int sb = ((ks * 4 + qd) ^ lr7) << 3;  // swizzled 16B slot in 64-el row
      bf16x8 af[4], b1f[2], b3f[2];
      for (int mi = 0; mi < 4; mi++)
        af[mi] = *(const bf16x8*)&As[(mw + mi * 16 + lr) * 64 + sb];
      for (int ni = 0; ni < 2; ni++) {
        b1f[ni] = *(const bf16x8*)&B1s[(nwv + ni * 16 + lr) * 64 + sb];
        b3f[ni] = *(const bf16x8*)&B3s[(nwv + ni * 16 + lr) * 64 + sb];
      }
      for (int mi = 0; mi < 4; mi++)
        for (int ni = 0; ni < 2; ni++) {
          accg[mi][ni] = __builtin_amdgcn_mfma_f32_16x16x32_bf16(af[mi], b1f[ni], accg[mi][ni], 0, 0, 0);
          accu[mi][ni] = __builtin_amdgcn_mfma_f32_16x16x32_bf16(af[mi], b3f[ni], accu[mi][ni], 0, 0, 0);
        }
    }
    __syncthreads();   // drains prefetch vmcnt + separates read(cur)/write(cur)
  }

  // C/D layout: row=(lane>>4)*4+reg, col=lane&15
  for (int mi = 0; mi < 4; mi++) {
    int rbase = row0 + mw + mi * 16 + qd * 4;
    for (int r = 0; r < 4; r++) {
      int grow = rbase + r;
      if (grow < rows_end) {
        for (int ni = 0; ni < 2; ni++) {
          float gg = accg[mi][ni][r], u = accu[mi][ni][r];
          float h = gg / (1.f + __expf(-gg)) * u;  // silu(g)*u
          hb[(size_t)grow * H_DIM + n0 + nwv + ni * 16 + lr] = f2bf_bits(h);
        }
      }
    }
  }
}

// ---- grouped GEMM 2 + fused combine: out[tok] += ew * (h @ w2) ----
// 128x64 tile, BK=64, 4 waves of 64x32, 2-phase double-buffered LDS (48 KB).
// Epilogue: fp32 atomicAdd into out (2 copies per token, commutative -> exact).
__global__ __launch_bounds__(256, 3) void gemm_out_kernel(
    const bfbits* __restrict__ hb, const bfbits* __restrict__ w2t,
    const int* __restrict__ meta, const int* __restrict__ row_src,
    const float* __restrict__ ew, float* __restrict__ out) {
  int nt = meta[17];
  int bt = blockIdx.y;
  if (bt >= nt) return;
  int e = meta[18 + bt];
  int row0 = meta[90 + bt];
  int rows_end = meta[e + 1];
  int n0 = blockIdx.x * 64;

  // per half (12288 bfbits): A [0,8192), B [8192,12288)
  __shared__ __align__(16) bfbits smbuf[2][12288];   // 48 KB

  int tid = threadIdx.x, lane = tid & 63, wv = tid >> 6;
  int r8 = lane >> 3, jl = lane & 7;
  int jg = jl ^ r8;

  // 24 staging segments: [0..15]=A rows (hb, pre-sorted), [16..23]=B rows
  const bfbits* gp[6]; int lpo[6];
  for (int j = 0; j < 6; j++) {
    int s = wv * 6 + j;
    if (s < 16) {
      gp[j] = hb + (size_t)(row0 + s * 8 + r8) * H_DIM + jg * 8;
      lpo[j] = s * 512;
    } else {
      int b = s - 16;
      gp[j] = w2t + ((size_t)e * D_MODEL + n0 + b * 8 + r8) * H_DIM + jg * 8;
      lpo[j] = 8192 + b * 512;
    }
  }

  const f32x4 fzero = {0.f, 0.f, 0.f, 0.f};
  f32x4 acc[4][2];
  for (int i = 0; i < 4; i++)
    for (int j = 0; j < 2; j++) acc[i][j] = fzero;

  int mw = (wv & 1) * 64, nwv = (wv >> 1) * 32;
  int qd = lane >> 4, lr = lane & 15, lr7 = lr & 7;

  // prologue: stage K-tile 0 into half 0
  for (int j = 0; j < 6; j++) glds16(gp[j], &smbuf[0][0] + lpo[j]);
  __syncthreads();

  for (int kk = 0; kk < H_DIM / 64; kk++) {
    int cur = kk & 1;
    if (kk < H_DIM / 64 - 1) {
      int ko = (kk + 1) * 64;
      bfbits* nx = &smbuf[cur ^ 1][0];
      for (int j = 0; j < 6; j++) glds16(gp[j] + ko, nx + lpo[j]);
    }
    const bfbits* As = &smbuf[cur][0];
    const bfbits* Bs = As + 8192;
    for (int ks = 0; ks < 2; ks++) {
      int sb = ((ks * 4 + qd) ^ lr7) << 3;
      bf16x8 af[4], bfr[2];
      for (int mi = 0; mi < 4; mi++)
        af[mi] = *(const bf16x8*)&As[(mw + mi * 16 + lr) * 64 + sb];
      for (int ni = 0; ni < 2; ni++)
        bfr[ni] = *(const bf16x8*)&Bs[(nwv + ni * 16 + lr) * 64 + sb];
      for (int mi = 0; mi < 4; mi++)
        for (int ni = 0; ni < 2; ni++)
          acc[mi][ni] = __builtin_amdgcn_mfma_f32_16x16x32_bf16(af[mi], bfr[ni], acc[mi][ni], 0, 0, 0);
    }
    __syncthreads();
  }

  // fused unpermute + weighted combine: out[tok, col] += ew[src] * acc
  for (int mi = 0; mi < 4; mi++) {
    int rbase = row0 + mw + mi * 16 + qd * 4;
    for (int r = 0; r < 4; r++) {
      int grow = rbase + r;
      if (grow < rows_end) {
        int src = row_src[grow];       // flat (token, k) index
        float w = ew[src];
        size_t ob = (size_t)(src >> 1) * D_MODEL + n0 + nwv + lr;
        for (int ni = 0; ni < 2; ni++)
          atomicAdd(&out[ob + ni * 16], w * acc[mi][ni][r]);
      }
    }
  }
}

extern "C" void kernel_launch(void* const* d_in, const int* in_sizes, int n_in,
                              void* d_out, int out_size, void* d_ws, size_t ws_size,
                              hipStream_t stream) {
  const float* x  = (const float*)d_in[0];
  const float* ew = (const float*)d_in[1];
  const int* eidx = (const int*)d_in[2];
  const int* bspe = (const int*)d_in[3];
  const float* w1 = (const float*)d_in[4];
  const float* w2 = (const float*)d_in[5];
  const float* w3 = (const float*)d_in[6];
  float* out = (float*)d_out;

  char* ws = (char*)d_ws;
  const size_t MB = 1024 * 1024;
  bfbits* w1t   = (bfbits*)(ws);             // 16 MB (E,H,D)
  bfbits* w3t   = (bfbits*)(ws + 16 * MB);   // 16 MB (E,H,D)
  bfbits* w2t   = (bfbits*)(ws + 32 * MB);   // 16 MB (E,D,H)
  bfbits* xb    = (bfbits*)(ws + 48 * MB);   //  8 MB (N,D)
  bfbits* hb    = (bfbits*)(ws + 56 * MB);   // 16 MB (NK,H)
  int* row_src  = (int*)(ws + 72 * MB);              // 32 KB
  int* pos_of   = (int*)(ws + 72 * MB + 32 * 1024);  // 32 KB
  int* meta     = (int*)(ws + 72 * MB + 64 * 1024);

  prepass_kernel<<<dim3(16, 8, 33), 256, 0, stream>>>(
      x, eidx, bspe, w1, w2, w3, w1t, w2t, w3t, xb, meta, row_src, pos_of,
      (float4*)out);
  gemm_swiglu_kernel<<<dim3(H_DIM / 64, MAX_TILES), 256, 0, stream>>>(
      xb, w1t, w3t, row_src, meta, hb);
  gemm_out_kernel<<<dim3(D_MODEL / 64, MAX_TILES), 256, 0, stream>>>(
      hb, w2t, meta, row_src, ew, out);
}

// Round 4
// 260.867 us; speedup vs baseline: 1.0161x; 1.0161x over previous
//
#include <hip/hip_runtime.h>
#include <hip/hip_bf16.h>
#include <stdint.h>

// Problem constants: N=4096, K=2, E=8, D=1024, H=1024
#define N_TOK   4096
#define TOPK    2
#define N_EXP   8
#define D_MODEL 1024
#define H_DIM   1024
#define NK      (N_TOK * TOPK)   // 8192 token-copies
#define MAX_TILES 72             // sum over experts of ceil(gs/128) <= 64+7

typedef __attribute__((ext_vector_type(8))) short bf16x8;  // 8 bf16 (4 VGPRs)
typedef __attribute__((ext_vector_type(4))) float f32x4;   // MFMA accumulator
typedef __attribute__((ext_vector_type(4))) unsigned int uint32x4;
typedef __attribute__((ext_vector_type(2))) unsigned int uint32x2;
typedef unsigned short bfbits;

__device__ inline bfbits f2bf_bits(float f) {
  union { float f; unsigned int u; } v; v.f = f;
  unsigned int r = v.u + 0x7FFFu + ((v.u >> 16) & 1u);  // RNE
  return (bfbits)(r >> 16);
}
__device__ inline float bf2f(unsigned short u) {
  union { unsigned int u; float f; } v; v.u = ((unsigned int)u) << 16;
  return v.f;
}

// async global->LDS, 16B/lane; LDS dest = wave-uniform base + lane*16
__device__ inline void glds16(const bfbits* g, bfbits* l) {
  __builtin_amdgcn_global_load_lds(
      (const __attribute__((address_space(1))) void*)g,
      (__attribute__((address_space(3))) void*)l, 16, 0, 0);
}

// ---- fused pre-pass ----
// z == 0       : (block 0,0 only) meta + bucket sort  (dispatched FIRST -> hides under bulk)
// 1 <= z <= 24 : transpose+convert weight matrix z-1 (w1:0-7, w3:8-15, w2:16-23)
//                128(rows) x 64(cols) tile per block, reg-staged, swizzled LDS
// 25 <= z <= 32: convert x -> bf16, 4 float4 per thread
// meta: [0..8] offs (excl scan), [17] ntiles, [18..89] tile_expert, [90..161] tile_row0
__global__ __launch_bounds__(256, 4) void prepass_kernel(
    const float* __restrict__ x, const int* __restrict__ eidx,
    const int* __restrict__ bspe,
    const float* __restrict__ w1, const float* __restrict__ w2,
    const float* __restrict__ w3,
    bfbits* __restrict__ w1t, bfbits* __restrict__ w2t,
    bfbits* __restrict__ w3t, bfbits* __restrict__ xb,
    int* __restrict__ meta, int* __restrict__ row_src,
    int* __restrict__ pos_of) {
  int z = blockIdx.z;
  int tid = threadIdx.x;

  if (z >= 1 && z <= 24) {
    // ---------- weight transpose + fp32->bf16 ----------
    int zz = z - 1;
    const size_t MAT = (size_t)1024 * 1024;
    const float* src; bfbits* dst;
    if (zz < 8)       { src = w1 + (size_t)zz * MAT;        dst = w1t + (size_t)zz * MAT; }
    else if (zz < 16) { src = w3 + (size_t)(zz - 8) * MAT;  dst = w3t + (size_t)(zz - 8) * MAT; }
    else              { src = w2 + (size_t)(zz - 16) * MAT; dst = w2t + (size_t)(zz - 16) * MAT; }

    // LDS tile stored TRANSPOSED: logical T[a][b], a = src col (0..63),
    // b = src row (0..127). Row pitch 264 B (132 shorts): 8B-aligned rows.
    // Bank swizzle: inner byte ^= ((a>>4)&3)<<3 (stays within the 264B row,
    // bijective; makes both packed writes and vector reads ~2-way).
    __shared__ __align__(16) bfbits Ts[64 * 132];   // 16.5 KB
    char* tsb = (char*)Ts;

    int r0 = blockIdx.y * 128, c0 = blockIdx.x * 64;
    int k = tid & 15, qw = tid >> 4;
    int c = k * 4;

    // phase 1: 8 independent float4 loads into regs (deep VMEM queue)
    float4 v0[4], v1[4];
#pragma unroll
    for (int it = 0; it < 4; it++) {
      int r = it * 32 + qw * 2;
      v0[it] = *(const float4*)&src[(size_t)(r0 + r) * 1024 + c0 + c];
      v1[it] = *(const float4*)&src[(size_t)(r0 + r + 1) * 1024 + c0 + c];
    }
    // phase 2: convert + packed ushort2 writes at transposed coords
#pragma unroll
    for (int it = 0; it < 4; it++) {
      int r = it * 32 + qw * 2;
      const float* a0 = (const float*)&v0[it];
      const float* a1 = (const float*)&v1[it];
#pragma unroll
      for (int j = 0; j < 4; j++) {
        int a = c + j;
        int xo = ((a >> 4) & 3) << 3;
        unsigned int pk = (unsigned int)f2bf_bits(a0[j]) |
                          ((unsigned int)f2bf_bits(a1[j]) << 16);
        *(unsigned int*)(tsb + a * 264 + ((r * 2) ^ xo)) = pk;
      }
    }
    __syncthreads();
    // phase 3: vector 8B LDS reads along output rows, 16B global stores
    int g = tid >> 3, m = tid & 7;
#pragma unroll
    for (int it2 = 0; it2 < 2; it2++) {
      int o = it2 * 32 + g;                 // output row = source col
      int base = o * 264;
      int xo = ((o >> 4) & 3) << 3;
      uint32x2 p0 = *(const uint32x2*)(tsb + base + ((m * 32 +  0) ^ xo));
      uint32x2 p1 = *(const uint32x2*)(tsb + base + ((m * 32 +  8) ^ xo));
      uint32x2 p2 = *(const uint32x2*)(tsb + base + ((m * 32 + 16) ^ xo));
      uint32x2 p3 = *(const uint32x2*)(tsb + base + ((m * 32 + 24) ^ xo));
      size_t ob = (size_t)(c0 + o) * 1024 + r0 + m * 16;
      uint32x4 s0; s0.x = p0.x; s0.y = p0.y; s0.z = p1.x; s0.w = p1.y;
      uint32x4 s1; s1.x = p2.x; s1.y = p2.y; s1.z = p3.x; s1.w = p3.y;
      *(uint32x4*)&dst[ob] = s0;
      *(uint32x4*)&dst[ob + 8] = s1;
    }
  } else if (z >= 25) {
    // ---------- x fp32 -> bf16, 4 float4 per thread ----------
    int idx = (z - 25) * 128 + blockIdx.y * 16 + blockIdx.x;  // 0..1023
    const float4* xv = (const float4*)x;
    ushort4* xo = (ushort4*)xb;
#pragma unroll
    for (int q = 0; q < 4; q++) {
      int fi = idx * 1024 + q * 256 + tid;
      float4 v = xv[fi];
      ushort4 o;
      o.x = f2bf_bits(v.x); o.y = f2bf_bits(v.y);
      o.z = f2bf_bits(v.z); o.w = f2bf_bits(v.w);
      xo[fi] = o;
    }
  } else {
    // ---------- z == 0: meta + bucket sort ----------
    if (blockIdx.x != 0 || blockIdx.y != 0) return;
    __shared__ int sm[162];
    __shared__ int scnt[N_EXP];
    if (tid == 0) {
      int acc = 0, nt = 0;
      for (int e = 0; e < N_EXP; e++) {
        sm[e] = acc;
        int g = bspe[e];
        for (int tt = 0; tt * 128 < g; tt++) {
          sm[18 + nt] = e;
          sm[90 + nt] = acc + tt * 128;
          nt++;
        }
        acc += g;
      }
      sm[8] = acc;
      sm[17] = nt;
      for (int i = nt; i < MAX_TILES; i++) { sm[18 + i] = 0; sm[90 + i] = 0; }
    }
    if (tid < N_EXP) scnt[tid] = 0;
    __syncthreads();
    // prefetch all expert indices first (8 int4 loads in flight), then bucket
    int4 eb[8];
#pragma unroll
    for (int q = 0; q < 8; q++) eb[q] = ((const int4*)eidx)[q * 256 + tid];
#pragma unroll
    for (int q = 0; q < 8; q++) {
      int ii = (q * 256 + tid) * 4;
      const int* ev = (const int*)&eb[q];
#pragma unroll
      for (int j = 0; j < 4; j++) {
        int e = ev[j];
        int p = sm[e] + atomicAdd(&scnt[e], 1);
        row_src[p] = ii + j;
        pos_of[ii + j] = p;
      }
    }
    if (tid < 162) meta[tid] = sm[tid];
  }
}

// ---- grouped GEMM 1: h = silu(x@w1) * (x@w3), bf16 out (NK,H) ----
// 128x128 tile, BK=64, 512 threads = 8 waves of 64x32, dual acc (64 AGPR).
// m97-style 2-barrier loop (implicit wave-level overlap; explicit dbuf
// measured neutral-to-worse). 48 KB LDS -> 3 blocks/CU, grid 8x72=576
// (~one residency wave -> minimal tail).
__global__ __launch_bounds__(512, 2) void gemm_swiglu_kernel(
    const bfbits* __restrict__ xb, const bfbits* __restrict__ w1t,
    const bfbits* __restrict__ w3t, const int* __restrict__ row_src,
    const int* __restrict__ meta, bfbits* __restrict__ hb) {
  int nt = meta[17];
  int bt = blockIdx.y;
  if (bt >= nt) return;
  int e = meta[18 + bt];
  int row0 = meta[90 + bt];
  int rows_end = meta[e + 1];
  int n0 = blockIdx.x * 128;

  __shared__ __align__(16) bfbits As[128 * 64];    // 16 KB
  __shared__ __align__(16) bfbits B1s[128 * 64];   // 16 KB
  __shared__ __align__(16) bfbits B3s[128 * 64];   // 16 KB

  int tid = threadIdx.x, lane = tid & 63, wv = tid >> 6;   // wv 0..7
  int r8 = lane >> 3, jl = lane & 7;
  int jg = jl ^ r8;   // swizzled global 16B chunk for this lane

  // 48 staging segments of 8 rows x 64 els: [0..15]=A, [16..31]=B1, [32..47]=B3
  const bfbits* gp[6]; bfbits* lp[6];
  for (int j = 0; j < 6; j++) {
    int s = wv * 6 + j;
    if (s < 16) {
      int tok = row_src[row0 + s * 8 + r8] >> 1;  // TOPK=2; rows>=rows_end read valid junk, discarded
      gp[j] = xb + (size_t)tok * D_MODEL + jg * 8;
      lp[j] = As + s * 512;
    } else if (s < 32) {
      int b = s - 16;
      gp[j] = w1t + ((size_t)e * H_DIM + n0 + b * 8 + r8) * D_MODEL + jg * 8;
      lp[j] = B1s + b * 512;
    } else {
      int b = s - 32;
      gp[j] = w3t + ((size_t)e * H_DIM + n0 + b * 8 + r8) * D_MODEL + jg * 8;
      lp[j] = B3s + b * 512;
    }
  }

  const f32x4 fzero = {0.f, 0.f, 0.f, 0.f};
  f32x4 accg[4][2], accu[4][2];
  for (int i = 0; i < 4; i++)
    for (int j = 0; j < 2; j++) { accg[i][j] = fzero; accu[i][j] = fzero; }

  int mw = (wv >> 2) * 64, nwv = (wv & 3) * 32;   // 2x4 wave grid over 128x128
  int qd = lane >> 4, lr = lane & 15, lr7 = lr & 7;

  for (int kk = 0; kk < D_MODEL / 64; kk++) {
    int ko = kk * 64;
    for (int j = 0; j < 6; j++) glds16(gp[j] + ko, lp[j]);
    __syncthreads();
    for (int ks = 0; ks < 2; ks++) {
      int sb = ((ks * 4 + qd) ^ lr7) << 3;  // swizzled 16B slot in 64-el row
      bf16x8 af[4], b1f[2], b3f[2];
      for (int mi = 0; mi < 4; mi++)
        af[mi] = *(const bf16x8*)&As[(mw + mi * 16 + lr) * 64 + sb];
      for (int ni = 0; ni < 2; ni++) {
        b1f[ni] = *(const bf16x8*)&B1s[(nwv + ni * 16 + lr) * 64 + sb];
        b3f[ni] = *(const bf16x8*)&B3s[(nwv + ni * 16 + lr) * 64 + sb];
      }
      for (int mi = 0; mi < 4; mi++)
        for (int ni = 0; ni < 2; ni++) {
          accg[mi][ni] = __builtin_amdgcn_mfma_f32_16x16x32_bf16(af[mi], b1f[ni], accg[mi][ni], 0, 0, 0);
          accu[mi][ni] = __builtin_amdgcn_mfma_f32_16x16x32_bf16(af[mi], b3f[ni], accu[mi][ni], 0, 0, 0);
        }
    }
    __syncthreads();
  }

  // C/D layout: row=(lane>>4)*4+reg, col=lane&15
  for (int mi = 0; mi < 4; mi++) {
    int rbase = row0 + mw + mi * 16 + qd * 4;
    for (int r = 0; r < 4; r++) {
      int grow = rbase + r;
      if (grow < rows_end) {
        for (int ni = 0; ni < 2; ni++) {
          float gg = accg[mi][ni][r], u = accu[mi][ni][r];
          float h = gg / (1.f + __expf(-gg)) * u;  // silu(g)*u
          hb[(size_t)grow * H_DIM + n0 + nwv + ni * 16 + lr] = f2bf_bits(h);
        }
      }
    }
  }
}

// ---- grouped GEMM 2: out_perm(bf16) = h @ w2 ----
// 128x128 tile, BK=64, 512 threads = 8 waves of 64x32, single acc (32 AGPR).
// 32 KB LDS -> 4 blocks/CU (wave cap), grid 8x72=576.
__global__ __launch_bounds__(512, 2) void gemm_out_kernel(
    const bfbits* __restrict__ hb, const bfbits* __restrict__ w2t,
    const int* __restrict__ meta, bfbits* __restrict__ out_perm) {
  int nt = meta[17];
  int bt = blockIdx.y;
  if (bt >= nt) return;
  int e = meta[18 + bt];
  int row0 = meta[90 + bt];
  int rows_end = meta[e + 1];
  int n0 = blockIdx.x * 128;

  __shared__ __align__(16) bfbits As[128 * 64];   // 16 KB
  __shared__ __align__(16) bfbits Bs[128 * 64];   // 16 KB

  int tid = threadIdx.x, lane = tid & 63, wv = tid >> 6;
  int r8 = lane >> 3, jl = lane & 7;
  int jg = jl ^ r8;

  // 32 staging segments: [0..15]=A rows (hb, pre-sorted), [16..31]=B rows
  const bfbits* gp[4]; bfbits* lp[4];
  for (int j = 0; j < 4; j++) {
    int s = wv * 4 + j;
    if (s < 16) {
      gp[j] = hb + (size_t)(row0 + s * 8 + r8) * H_DIM + jg * 8;
      lp[j] = As + s * 512;
    } else {
      int b = s - 16;
      gp[j] = w2t + ((size_t)e * D_MODEL + n0 + b * 8 + r8) * H_DIM + jg * 8;
      lp[j] = Bs + b * 512;
    }
  }

  const f32x4 fzero = {0.f, 0.f, 0.f, 0.f};
  f32x4 acc[4][2];
  for (int i = 0; i < 4; i++)
    for (int j = 0; j < 2; j++) acc[i][j] = fzero;

  int mw = (wv >> 2) * 64, nwv = (wv & 3) * 32;
  int qd = lane >> 4, lr = lane & 15, lr7 = lr & 7;

  for (int kk = 0; kk < H_DIM / 64; kk++) {
    int ko = kk * 64;
    for (int j = 0; j < 4; j++) glds16(gp[j] + ko, lp[j]);
    __syncthreads();
    for (int ks = 0; ks < 2; ks++) {
      int sb = ((ks * 4 + qd) ^ lr7) << 3;
      bf16x8 af[4], bfr[2];
      for (int mi = 0; mi < 4; mi++)
        af[mi] = *(const bf16x8*)&As[(mw + mi * 16 + lr) * 64 + sb];
      for (int ni = 0; ni < 2; ni++)
        bfr[ni] = *(const bf16x8*)&Bs[(nwv + ni * 16 + lr) * 64 + sb];
      for (int mi = 0; mi < 4; mi++)
        for (int ni = 0; ni < 2; ni++)
          acc[mi][ni] = __builtin_amdgcn_mfma_f32_16x16x32_bf16(af[mi], bfr[ni], acc[mi][ni], 0, 0, 0);
    }
    __syncthreads();
  }

  for (int mi = 0; mi < 4; mi++) {
    int rbase = row0 + mw + mi * 16 + qd * 4;
    for (int r = 0; r < 4; r++) {
      int grow = rbase + r;
      if (grow < rows_end) {
        for (int ni = 0; ni < 2; ni++)
          out_perm[(size_t)grow * D_MODEL + n0 + nwv + ni * 16 + lr] = f2bf_bits(acc[mi][ni][r]);
      }
    }
  }
}

// ---- weighted combine of the two copies per token (bf16 in, fp32 out) ----
// 4 float4 per thread; within an iteration all threads share one token ->
// pos_of/ew loads are wave-uniform (scalar).
__global__ __launch_bounds__(256) void combine_kernel(
    const ushort4* __restrict__ out_perm, const int* __restrict__ pos_of,
    const float* __restrict__ ew, float4* __restrict__ out) {
  int tid = threadIdx.x;
#pragma unroll
  for (int q = 0; q < 4; q++) {
    int i = blockIdx.x * 1024 + q * 256 + tid;  // over N_TOK * D/4
    int tok = i >> 8;                            // D/4 = 256
    int col = i & 255;
    int p0 = pos_of[2 * tok], p1 = pos_of[2 * tok + 1];
    float w0 = ew[2 * tok], w1 = ew[2 * tok + 1];
    ushort4 a = out_perm[(size_t)p0 * 256 + col];
    ushort4 b = out_perm[(size_t)p1 * 256 + col];
    float4 o;
    o.x = w0 * bf2f(a.x) + w1 * bf2f(b.x);
    o.y = w0 * bf2f(a.y) + w1 * bf2f(b.y);
    o.z = w0 * bf2f(a.z) + w1 * bf2f(b.z);
    o.w = w0 * bf2f(a.w) + w1 * bf2f(b.w);
    out[i] = o;
  }
}

extern "C" void kernel_launch(void* const* d_in, const int* in_sizes, int n_in,
                              void* d_out, int out_size, void* d_ws, size_t ws_size,
                              hipStream_t stream) {
  const float* x  = (const float*)d_in[0];
  const float* ew = (const float*)d_in[1];
  const int* eidx = (const int*)d_in[2];
  const int* bspe = (const int*)d_in[3];
  const float* w1 = (const float*)d_in[4];
  const float* w2 = (const float*)d_in[5];
  const float* w3 = (const float*)d_in[6];
  float* out = (float*)d_out;

  char* ws = (char*)d_ws;
  const size_t MB = 1024 * 1024;
  bfbits* w1t   = (bfbits*)(ws);             // 16 MB (E,H,D)
  bfbits* w3t   = (bfbits*)(ws + 16 * MB);   // 16 MB (E,H,D)
  bfbits* w2t   = (bfbits*)(ws + 32 * MB);   // 16 MB (E,D,H)
  bfbits* xb    = (bfbits*)(ws + 48 * MB);   //  8 MB (N,D)
  bfbits* hb    = (bfbits*)(ws + 56 * MB);   // 16 MB (NK,H)
  // out_perm (16 MB bf16) aliases w1t — dead after gemm_swiglu completes
  bfbits* out_perm = (bfbits*)(ws);
  int* row_src  = (int*)(ws + 72 * MB);              // 32 KB
  int* pos_of   = (int*)(ws + 72 * MB + 32 * 1024);  // 32 KB
  int* meta     = (int*)(ws + 72 * MB + 64 * 1024);

  prepass_kernel<<<dim3(16, 8, 33), 256, 0, stream>>>(
      x, eidx, bspe, w1, w2, w3, w1t, w2t, w3t, xb, meta, row_src, pos_of);
  gemm_swiglu_kernel<<<dim3(H_DIM / 128, MAX_TILES), 512, 0, stream>>>(
      xb, w1t, w3t, row_src, meta, hb);
  gemm_out_kernel<<<dim3(D_MODEL / 128, MAX_TILES), 512, 0, stream>>>(
      hb, w2t, meta, out_perm);
  combine_kernel<<<(N_TOK * D_MODEL / 4) / 1024, 256, 0, stream>>>(
      (const ushort4*)out_perm, pos_of, ew, (float4*)out);
}

// Round 5
// 240.066 us; speedup vs baseline: 1.1042x; 1.0866x over previous
//
#include <hip/hip_runtime.h>
#include <hip/hip_bf16.h>
#include <stdint.h>

// Problem constants: N=4096, K=2, E=8, D=1024, H=1024
#define N_TOK   4096
#define TOPK    2
#define N_EXP   8
#define D_MODEL 1024
#define H_DIM   1024
#define NK      (N_TOK * TOPK)   // 8192 token-copies
#define MAX_TILES 72             // sum over experts of ceil(gs/128) <= 64+7

typedef __attribute__((ext_vector_type(8))) short bf16x8;  // 8 bf16 (4 VGPRs)
typedef __attribute__((ext_vector_type(4))) float f32x4;   // MFMA accumulator
typedef __attribute__((ext_vector_type(4))) unsigned int uint32x4;
typedef __attribute__((ext_vector_type(2))) unsigned int uint32x2;
typedef unsigned short bfbits;

__device__ inline bfbits f2bf_bits(float f) {
  union { float f; unsigned int u; } v; v.f = f;
  unsigned int r = v.u + 0x7FFFu + ((v.u >> 16) & 1u);  // RNE
  return (bfbits)(r >> 16);
}
__device__ inline float bf2f(unsigned short u) {
  union { unsigned int u; float f; } v; v.u = ((unsigned int)u) << 16;
  return v.f;
}

// async global->LDS, 16B/lane; LDS dest = wave-uniform base + lane*16
__device__ inline void glds16(const bfbits* g, bfbits* l) {
  __builtin_amdgcn_global_load_lds(
      (const __attribute__((address_space(1))) void*)g,
      (__attribute__((address_space(3))) void*)l, 16, 0, 0);
}

// ---- fused pre-pass ----
// z == 0       : (block 0,0 only) meta + bucket sort  (dispatched FIRST -> hides under bulk)
// 1 <= z <= 24 : transpose+convert weight matrix z-1 (w1:0-7, w3:8-15, w2:16-23)
//                128(rows) x 64(cols) tile per block, reg-staged, swizzled LDS
// 25 <= z <= 32: convert x -> bf16, 4 float4 per thread
// meta: [0..8] offs (excl scan), [17] ntiles, [18..89] tile_expert, [90..161] tile_row0
__global__ __launch_bounds__(256, 4) void prepass_kernel(
    const float* __restrict__ x, const int* __restrict__ eidx,
    const int* __restrict__ bspe,
    const float* __restrict__ w1, const float* __restrict__ w2,
    const float* __restrict__ w3,
    bfbits* __restrict__ w1t, bfbits* __restrict__ w2t,
    bfbits* __restrict__ w3t, bfbits* __restrict__ xb,
    int* __restrict__ meta, int* __restrict__ row_src,
    int* __restrict__ pos_of) {
  int z = blockIdx.z;
  int tid = threadIdx.x;

  if (z >= 1 && z <= 24) {
    // ---------- weight transpose + fp32->bf16 ----------
    int zz = z - 1;
    const size_t MAT = (size_t)1024 * 1024;
    const float* src; bfbits* dst;
    if (zz < 8)       { src = w1 + (size_t)zz * MAT;        dst = w1t + (size_t)zz * MAT; }
    else if (zz < 16) { src = w3 + (size_t)(zz - 8) * MAT;  dst = w3t + (size_t)(zz - 8) * MAT; }
    else              { src = w2 + (size_t)(zz - 16) * MAT; dst = w2t + (size_t)(zz - 16) * MAT; }

    // LDS tile stored TRANSPOSED: logical T[a][b], a = src col (0..63),
    // b = src row (0..127). Row pitch 264 B (132 shorts): 8B-aligned rows.
    // Bank swizzle: inner byte ^= ((a>>4)&3)<<3 (stays within the 264B row,
    // bijective; makes both packed writes and vector reads ~2-way).
    __shared__ __align__(16) bfbits Ts[64 * 132];   // 16.5 KB
    char* tsb = (char*)Ts;

    int r0 = blockIdx.y * 128, c0 = blockIdx.x * 64;
    int k = tid & 15, qw = tid >> 4;
    int c = k * 4;

    // phase 1: 8 independent float4 loads into regs (deep VMEM queue)
    float4 v0[4], v1[4];
#pragma unroll
    for (int it = 0; it < 4; it++) {
      int r = it * 32 + qw * 2;
      v0[it] = *(const float4*)&src[(size_t)(r0 + r) * 1024 + c0 + c];
      v1[it] = *(const float4*)&src[(size_t)(r0 + r + 1) * 1024 + c0 + c];
    }
    // phase 2: convert + packed ushort2 writes at transposed coords
#pragma unroll
    for (int it = 0; it < 4; it++) {
      int r = it * 32 + qw * 2;
      const float* a0 = (const float*)&v0[it];
      const float* a1 = (const float*)&v1[it];
#pragma unroll
      for (int j = 0; j < 4; j++) {
        int a = c + j;
        int xo = ((a >> 4) & 3) << 3;
        unsigned int pk = (unsigned int)f2bf_bits(a0[j]) |
                          ((unsigned int)f2bf_bits(a1[j]) << 16);
        *(unsigned int*)(tsb + a * 264 + ((r * 2) ^ xo)) = pk;
      }
    }
    __syncthreads();
    // phase 3: vector 8B LDS reads along output rows, 16B global stores
    int g = tid >> 3, m = tid & 7;
#pragma unroll
    for (int it2 = 0; it2 < 2; it2++) {
      int o = it2 * 32 + g;                 // output row = source col
      int base = o * 264;
      int xo = ((o >> 4) & 3) << 3;
      uint32x2 p0 = *(const uint32x2*)(tsb + base + ((m * 32 +  0) ^ xo));
      uint32x2 p1 = *(const uint32x2*)(tsb + base + ((m * 32 +  8) ^ xo));
      uint32x2 p2 = *(const uint32x2*)(tsb + base + ((m * 32 + 16) ^ xo));
      uint32x2 p3 = *(const uint32x2*)(tsb + base + ((m * 32 + 24) ^ xo));
      size_t ob = (size_t)(c0 + o) * 1024 + r0 + m * 16;
      uint32x4 s0; s0.x = p0.x; s0.y = p0.y; s0.z = p1.x; s0.w = p1.y;
      uint32x4 s1; s1.x = p2.x; s1.y = p2.y; s1.z = p3.x; s1.w = p3.y;
      *(uint32x4*)&dst[ob] = s0;
      *(uint32x4*)&dst[ob + 8] = s1;
    }
  } else if (z >= 25) {
    // ---------- x fp32 -> bf16, 4 float4 per thread ----------
    int idx = (z - 25) * 128 + blockIdx.y * 16 + blockIdx.x;  // 0..1023
    const float4* xv = (const float4*)x;
    ushort4* xo = (ushort4*)xb;
#pragma unroll
    for (int q = 0; q < 4; q++) {
      int fi = idx * 1024 + q * 256 + tid;
      float4 v = xv[fi];
      ushort4 o;
      o.x = f2bf_bits(v.x); o.y = f2bf_bits(v.y);
      o.z = f2bf_bits(v.z); o.w = f2bf_bits(v.w);
      xo[fi] = o;
    }
  } else {
    // ---------- z == 0: meta + bucket sort ----------
    if (blockIdx.x != 0 || blockIdx.y != 0) return;
    __shared__ int sm[162];
    __shared__ int scnt[N_EXP];
    if (tid == 0) {
      int acc = 0, nt = 0;
      for (int e = 0; e < N_EXP; e++) {
        sm[e] = acc;
        int g = bspe[e];
        for (int tt = 0; tt * 128 < g; tt++) {
          sm[18 + nt] = e;
          sm[90 + nt] = acc + tt * 128;
          nt++;
        }
        acc += g;
      }
      sm[8] = acc;
      sm[17] = nt;
      for (int i = nt; i < MAX_TILES; i++) { sm[18 + i] = 0; sm[90 + i] = 0; }
    }
    if (tid < N_EXP) scnt[tid] = 0;
    __syncthreads();
    // prefetch all expert indices first (8 int4 loads in flight), then bucket
    int4 eb[8];
#pragma unroll
    for (int q = 0; q < 8; q++) eb[q] = ((const int4*)eidx)[q * 256 + tid];
#pragma unroll
    for (int q = 0; q < 8; q++) {
      int ii = (q * 256 + tid) * 4;
      const int* ev = (const int*)&eb[q];
#pragma unroll
      for (int j = 0; j < 4; j++) {
        int e = ev[j];
        int p = sm[e] + atomicAdd(&scnt[e], 1);
        row_src[p] = ii + j;
        pos_of[ii + j] = p;
      }
    }
    if (tid < 162) meta[tid] = sm[tid];
  }
}

// ---- grouped GEMM 1: h = silu(x@w1) * (x@w3), bf16 out (NK,H) ----
// 128x64 tile, BK=64, 4 waves of 64x32, dual acc (64 AGPR).
// Proven round-2 config (52.7 us): 2-barrier loop, glds staging, XOR swizzle.
__global__ __launch_bounds__(256, 3) void gemm_swiglu_kernel(
    const bfbits* __restrict__ xb, const bfbits* __restrict__ w1t,
    const bfbits* __restrict__ w3t, const int* __restrict__ row_src,
    const int* __restrict__ meta, bfbits* __restrict__ hb) {
  int nt = meta[17];
  int bt = blockIdx.y;
  if (bt >= nt) return;
  int e = meta[18 + bt];
  int row0 = meta[90 + bt];
  int rows_end = meta[e + 1];
  int n0 = blockIdx.x * 64;

  __shared__ __align__(16) bfbits As[128 * 64];   // 16 KB
  __shared__ __align__(16) bfbits B1s[64 * 64];   //  8 KB
  __shared__ __align__(16) bfbits B3s[64 * 64];   //  8 KB

  int tid = threadIdx.x, lane = tid & 63, wv = tid >> 6;
  int r8 = lane >> 3, jl = lane & 7;
  int jg = jl ^ r8;   // swizzled global 16B chunk for this lane

  // 32 staging segments of 8 rows each: [0..15]=A, [16..23]=B1, [24..31]=B3
  const bfbits* gp[8]; bfbits* lp[8];
  for (int j = 0; j < 8; j++) {
    int s = wv * 8 + j;
    if (s < 16) {
      int tok = row_src[row0 + s * 8 + r8] >> 1;  // TOPK=2; rows>=rows_end read valid junk, discarded
      gp[j] = xb + (size_t)tok * D_MODEL + jg * 8;
      lp[j] = As + s * 512;
    } else if (s < 24) {
      int b = s - 16;
      gp[j] = w1t + ((size_t)e * H_DIM + n0 + b * 8 + r8) * D_MODEL + jg * 8;
      lp[j] = B1s + b * 512;
    } else {
      int b = s - 24;
      gp[j] = w3t + ((size_t)e * H_DIM + n0 + b * 8 + r8) * D_MODEL + jg * 8;
      lp[j] = B3s + b * 512;
    }
  }

  const f32x4 fzero = {0.f, 0.f, 0.f, 0.f};
  f32x4 accg[4][2], accu[4][2];
  for (int i = 0; i < 4; i++)
    for (int j = 0; j < 2; j++) { accg[i][j] = fzero; accu[i][j] = fzero; }

  int mw = (wv & 1) * 64, nwv = (wv >> 1) * 32;
  int qd = lane >> 4, lr = lane & 15, lr7 = lr & 7;

  for (int kk = 0; kk < D_MODEL / 64; kk++) {
    int ko = kk * 64;
    for (int j = 0; j < 8; j++) glds16(gp[j] + ko, lp[j]);
    __syncthreads();
    for (int ks = 0; ks < 2; ks++) {
      int sb = ((ks * 4 + qd) ^ lr7) << 3;  // swizzled 16B slot in 64-el row
      bf16x8 af[4], b1f[2], b3f[2];
      for (int mi = 0; mi < 4; mi++)
        af[mi] = *(const bf16x8*)&As[(mw + mi * 16 + lr) * 64 + sb];
      for (int ni = 0; ni < 2; ni++) {
        b1f[ni] = *(const bf16x8*)&B1s[(nwv + ni * 16 + lr) * 64 + sb];
        b3f[ni] = *(const bf16x8*)&B3s[(nwv + ni * 16 + lr) * 64 + sb];
      }
      for (int mi = 0; mi < 4; mi++)
        for (int ni = 0; ni < 2; ni++) {
          accg[mi][ni] = __builtin_amdgcn_mfma_f32_16x16x32_bf16(af[mi], b1f[ni], accg[mi][ni], 0, 0, 0);
          accu[mi][ni] = __builtin_amdgcn_mfma_f32_16x16x32_bf16(af[mi], b3f[ni], accu[mi][ni], 0, 0, 0);
        }
    }
    __syncthreads();
  }

  // C/D layout: row=(lane>>4)*4+reg, col=lane&15
  for (int mi = 0; mi < 4; mi++) {
    int rbase = row0 + mw + mi * 16 + qd * 4;
    for (int r = 0; r < 4; r++) {
      int grow = rbase + r;
      if (grow < rows_end) {
        for (int ni = 0; ni < 2; ni++) {
          float gg = accg[mi][ni][r], u = accu[mi][ni][r];
          float h = gg / (1.f + __expf(-gg)) * u;  // silu(g)*u
          hb[(size_t)grow * H_DIM + n0 + nwv + ni * 16 + lr] = f2bf_bits(h);
        }
      }
    }
  }
}

// ---- grouped GEMM 2: out_perm(bf16) = h @ w2 ----
// m97-exact shape: 128x128 tile, BK=64, 256 threads = 4 waves of 64x64,
// acc[4][4] (64 AGPR). 16 MFMA per 8 ds_reads per ks -> 2x the
// MFMA-per-barrier density of the 128x64 version. 32 KB LDS, grid 8x72.
__global__ __launch_bounds__(256, 2) void gemm_out_kernel(
    const bfbits* __restrict__ hb, const bfbits* __restrict__ w2t,
    const int* __restrict__ meta, bfbits* __restrict__ out_perm) {
  int nt = meta[17];
  int bt = blockIdx.y;
  if (bt >= nt) return;
  int e = meta[18 + bt];
  int row0 = meta[90 + bt];
  int rows_end = meta[e + 1];
  int n0 = blockIdx.x * 128;

  __shared__ __align__(16) bfbits As[128 * 64];   // 16 KB
  __shared__ __align__(16) bfbits Bs[128 * 64];   // 16 KB

  int tid = threadIdx.x, lane = tid & 63, wv = tid >> 6;
  int r8 = lane >> 3, jl = lane & 7;
  int jg = jl ^ r8;

  // 32 staging segments of 8 rows: [0..15]=A rows (hb, pre-sorted), [16..31]=B rows
  const bfbits* gp[8]; bfbits* lp[8];
  for (int j = 0; j < 8; j++) {
    int s = wv * 8 + j;
    if (s < 16) {
      gp[j] = hb + (size_t)(row0 + s * 8 + r8) * H_DIM + jg * 8;
      lp[j] = As + s * 512;
    } else {
      int b = s - 16;
      gp[j] = w2t + ((size_t)e * D_MODEL + n0 + b * 8 + r8) * H_DIM + jg * 8;
      lp[j] = Bs + b * 512;
    }
  }

  const f32x4 fzero = {0.f, 0.f, 0.f, 0.f};
  f32x4 acc[4][4];
  for (int i = 0; i < 4; i++)
    for (int j = 0; j < 4; j++) acc[i][j] = fzero;

  int mw = (wv & 1) * 64, nw = (wv >> 1) * 64;   // 2x2 wave grid, 64x64 each
  int qd = lane >> 4, lr = lane & 15, lr7 = lr & 7;

  for (int kk = 0; kk < H_DIM / 64; kk++) {
    int ko = kk * 64;
    for (int j = 0; j < 8; j++) glds16(gp[j] + ko, lp[j]);
    __syncthreads();
    for (int ks = 0; ks < 2; ks++) {
      int sb = ((ks * 4 + qd) ^ lr7) << 3;
      bf16x8 af[4], bfr[4];
      for (int mi = 0; mi < 4; mi++)
        af[mi] = *(const bf16x8*)&As[(mw + mi * 16 + lr) * 64 + sb];
      for (int ni = 0; ni < 4; ni++)
        bfr[ni] = *(const bf16x8*)&Bs[(nw + ni * 16 + lr) * 64 + sb];
      for (int mi = 0; mi < 4; mi++)
        for (int ni = 0; ni < 4; ni++)
          acc[mi][ni] = __builtin_amdgcn_mfma_f32_16x16x32_bf16(af[mi], bfr[ni], acc[mi][ni], 0, 0, 0);
    }
    __syncthreads();
  }

  for (int mi = 0; mi < 4; mi++) {
    int rbase = row0 + mw + mi * 16 + qd * 4;
    for (int r = 0; r < 4; r++) {
      int grow = rbase + r;
      if (grow < rows_end) {
        for (int ni = 0; ni < 4; ni++)
          out_perm[(size_t)grow * D_MODEL + n0 + nw + ni * 16 + lr] = f2bf_bits(acc[mi][ni][r]);
      }
    }
  }
}

// ---- weighted combine of the two copies per token (bf16 in, fp32 out) ----
// 4 float4 per thread; within an iteration all threads share one token ->
// pos_of/ew loads are wave-uniform (scalar).
__global__ __launch_bounds__(256) void combine_kernel(
    const ushort4* __restrict__ out_perm, const int* __restrict__ pos_of,
    const float* __restrict__ ew, float4* __restrict__ out) {
  int tid = threadIdx.x;
#pragma unroll
  for (int q = 0; q < 4; q++) {
    int i = blockIdx.x * 1024 + q * 256 + tid;  // over N_TOK * D/4
    int tok = i >> 8;                            // D/4 = 256
    int col = i & 255;
    int p0 = pos_of[2 * tok], p1 = pos_of[2 * tok + 1];
    float w0 = ew[2 * tok], w1 = ew[2 * tok + 1];
    ushort4 a = out_perm[(size_t)p0 * 256 + col];
    ushort4 b = out_perm[(size_t)p1 * 256 + col];
    float4 o;
    o.x = w0 * bf2f(a.x) + w1 * bf2f(b.x);
    o.y = w0 * bf2f(a.y) + w1 * bf2f(b.y);
    o.z = w0 * bf2f(a.z) + w1 * bf2f(b.z);
    o.w = w0 * bf2f(a.w) + w1 * bf2f(b.w);
    out[i] = o;
  }
}

extern "C" void kernel_launch(void* const* d_in, const int* in_sizes, int n_in,
                              void* d_out, int out_size, void* d_ws, size_t ws_size,
                              hipStream_t stream) {
  const float* x  = (const float*)d_in[0];
  const float* ew = (const float*)d_in[1];
  const int* eidx = (const int*)d_in[2];
  const int* bspe = (const int*)d_in[3];
  const float* w1 = (const float*)d_in[4];
  const float* w2 = (const float*)d_in[5];
  const float* w3 = (const float*)d_in[6];
  float* out = (float*)d_out;

  char* ws = (char*)d_ws;
  const size_t MB = 1024 * 1024;
  bfbits* w1t   = (bfbits*)(ws);             // 16 MB (E,H,D)
  bfbits* w3t   = (bfbits*)(ws + 16 * MB);   // 16 MB (E,H,D)
  bfbits* w2t   = (bfbits*)(ws + 32 * MB);   // 16 MB (E,D,H)
  bfbits* xb    = (bfbits*)(ws + 48 * MB);   //  8 MB (N,D)
  bfbits* hb    = (bfbits*)(ws + 56 * MB);   // 16 MB (NK,H)
  // out_perm (16 MB bf16) aliases w1t — dead after gemm_swiglu completes
  bfbits* out_perm = (bfbits*)(ws);
  int* row_src  = (int*)(ws + 72 * MB);              // 32 KB
  int* pos_of   = (int*)(ws + 72 * MB + 32 * 1024);  // 32 KB
  int* meta     = (int*)(ws + 72 * MB + 64 * 1024);

  prepass_kernel<<<dim3(16, 8, 33), 256, 0, stream>>>(
      x, eidx, bspe, w1, w2, w3, w1t, w2t, w3t, xb, meta, row_src, pos_of);
  gemm_swiglu_kernel<<<dim3(H_DIM / 64, MAX_TILES), 256, 0, stream>>>(
      xb, w1t, w3t, row_src, meta, hb);
  gemm_out_kernel<<<dim3(D_MODEL / 128, MAX_TILES), 256, 0, stream>>>(
      hb, w2t, meta, out_perm);
  combine_kernel<<<(N_TOK * D_MODEL / 4) / 1024, 256, 0, stream>>>(
      (const ushort4*)out_perm, pos_of, ew, (float4*)out);
}

// Round 6
// 237.422 us; speedup vs baseline: 1.1165x; 1.0111x over previous
//
#include <hip/hip_runtime.h>
#include <hip/hip_bf16.h>
#include <stdint.h>

// Problem constants: N=4096, K=2, E=8, D=1024, H=1024
#define N_TOK   4096
#define TOPK    2
#define N_EXP   8
#define D_MODEL 1024
#define H_DIM   1024
#define NK      (N_TOK * TOPK)   // 8192 token-copies
#define MAX_TILES 72             // sum over experts of ceil(gs/128) <= 64+7

typedef __attribute__((ext_vector_type(8))) short bf16x8;  // 8 bf16 (4 VGPRs)
typedef __attribute__((ext_vector_type(4))) float f32x4;   // MFMA accumulator
typedef __attribute__((ext_vector_type(4))) unsigned int uint32x4;
typedef __attribute__((ext_vector_type(2))) unsigned int uint32x2;
typedef unsigned short bfbits;

__device__ inline bfbits f2bf_bits(float f) {
  union { float f; unsigned int u; } v; v.f = f;
  unsigned int r = v.u + 0x7FFFu + ((v.u >> 16) & 1u);  // RNE
  return (bfbits)(r >> 16);
}
__device__ inline float bf2f(unsigned short u) {
  union { unsigned int u; float f; } v; v.u = ((unsigned int)u) << 16;
  return v.f;
}

// async global->LDS, 16B/lane; LDS dest = wave-uniform base + lane*16
__device__ inline void glds16(const bfbits* g, bfbits* l) {
  __builtin_amdgcn_global_load_lds(
      (const __attribute__((address_space(1))) void*)g,
      (__attribute__((address_space(3))) void*)l, 16, 0, 0);
}

// ---- fused pre-pass ----
// z == 0       : (block 0,0 only) meta + bucket sort  (dispatched FIRST -> hides under bulk)
// 1 <= z <= 24 : transpose+convert weight matrix z-1 (w1:0-7, w3:8-15, w2:16-23)
//                128(rows) x 64(cols) tile per block, reg-staged, swizzled LDS
// 25 <= z <= 32: convert x -> bf16, 4 float4 per thread
// meta: [0..8] offs (excl scan), [17] ntiles, [18..89] tile_expert, [90..161] tile_row0
__global__ __launch_bounds__(256, 4) void prepass_kernel(
    const float* __restrict__ x, const int* __restrict__ eidx,
    const int* __restrict__ bspe,
    const float* __restrict__ w1, const float* __restrict__ w2,
    const float* __restrict__ w3,
    bfbits* __restrict__ w1t, bfbits* __restrict__ w2t,
    bfbits* __restrict__ w3t, bfbits* __restrict__ xb,
    int* __restrict__ meta, int* __restrict__ row_src,
    int* __restrict__ pos_of) {
  int z = blockIdx.z;
  int tid = threadIdx.x;

  if (z >= 1 && z <= 24) {
    // ---------- weight transpose + fp32->bf16 ----------
    int zz = z - 1;
    const size_t MAT = (size_t)1024 * 1024;
    const float* src; bfbits* dst;
    if (zz < 8)       { src = w1 + (size_t)zz * MAT;        dst = w1t + (size_t)zz * MAT; }
    else if (zz < 16) { src = w3 + (size_t)(zz - 8) * MAT;  dst = w3t + (size_t)(zz - 8) * MAT; }
    else              { src = w2 + (size_t)(zz - 16) * MAT; dst = w2t + (size_t)(zz - 16) * MAT; }

    // LDS tile stored TRANSPOSED: logical T[a][b], a = src col (0..63),
    // b = src row (0..127). Row pitch 264 B (132 shorts): 8B-aligned rows.
    // Bank swizzle: inner byte ^= ((a>>4)&3)<<3 (stays within the 264B row,
    // bijective; makes both packed writes and vector reads ~2-way).
    __shared__ __align__(16) bfbits Ts[64 * 132];   // 16.5 KB
    char* tsb = (char*)Ts;

    int r0 = blockIdx.y * 128, c0 = blockIdx.x * 64;
    int k = tid & 15, qw = tid >> 4;
    int c = k * 4;

    // phase 1: 8 independent float4 loads into regs (deep VMEM queue)
    float4 v0[4], v1[4];
#pragma unroll
    for (int it = 0; it < 4; it++) {
      int r = it * 32 + qw * 2;
      v0[it] = *(const float4*)&src[(size_t)(r0 + r) * 1024 + c0 + c];
      v1[it] = *(const float4*)&src[(size_t)(r0 + r + 1) * 1024 + c0 + c];
    }
    // phase 2: convert + packed ushort2 writes at transposed coords
#pragma unroll
    for (int it = 0; it < 4; it++) {
      int r = it * 32 + qw * 2;
      const float* a0 = (const float*)&v0[it];
      const float* a1 = (const float*)&v1[it];
#pragma unroll
      for (int j = 0; j < 4; j++) {
        int a = c + j;
        int xo = ((a >> 4) & 3) << 3;
        unsigned int pk = (unsigned int)f2bf_bits(a0[j]) |
                          ((unsigned int)f2bf_bits(a1[j]) << 16);
        *(unsigned int*)(tsb + a * 264 + ((r * 2) ^ xo)) = pk;
      }
    }
    __syncthreads();
    // phase 3: vector 8B LDS reads along output rows, 16B global stores
    int g = tid >> 3, m = tid & 7;
#pragma unroll
    for (int it2 = 0; it2 < 2; it2++) {
      int o = it2 * 32 + g;                 // output row = source col
      int base = o * 264;
      int xo = ((o >> 4) & 3) << 3;
      uint32x2 p0 = *(const uint32x2*)(tsb + base + ((m * 32 +  0) ^ xo));
      uint32x2 p1 = *(const uint32x2*)(tsb + base + ((m * 32 +  8) ^ xo));
      uint32x2 p2 = *(const uint32x2*)(tsb + base + ((m * 32 + 16) ^ xo));
      uint32x2 p3 = *(const uint32x2*)(tsb + base + ((m * 32 + 24) ^ xo));
      size_t ob = (size_t)(c0 + o) * 1024 + r0 + m * 16;
      uint32x4 s0; s0.x = p0.x; s0.y = p0.y; s0.z = p1.x; s0.w = p1.y;
      uint32x4 s1; s1.x = p2.x; s1.y = p2.y; s1.z = p3.x; s1.w = p3.y;
      *(uint32x4*)&dst[ob] = s0;
      *(uint32x4*)&dst[ob + 8] = s1;
    }
  } else if (z >= 25) {
    // ---------- x fp32 -> bf16, 4 float4 per thread ----------
    int idx = (z - 25) * 128 + blockIdx.y * 16 + blockIdx.x;  // 0..1023
    const float4* xv = (const float4*)x;
    ushort4* xo = (ushort4*)xb;
#pragma unroll
    for (int q = 0; q < 4; q++) {
      int fi = idx * 1024 + q * 256 + tid;
      float4 v = xv[fi];
      ushort4 o;
      o.x = f2bf_bits(v.x); o.y = f2bf_bits(v.y);
      o.z = f2bf_bits(v.z); o.w = f2bf_bits(v.w);
      xo[fi] = o;
    }
  } else {
    // ---------- z == 0: meta + bucket sort ----------
    if (blockIdx.x != 0 || blockIdx.y != 0) return;
    __shared__ int sm[162];
    __shared__ int scnt[N_EXP];
    if (tid == 0) {
      int acc = 0, nt = 0;
      for (int e = 0; e < N_EXP; e++) {
        sm[e] = acc;
        int g = bspe[e];
        for (int tt = 0; tt * 128 < g; tt++) {
          sm[18 + nt] = e;
          sm[90 + nt] = acc + tt * 128;
          nt++;
        }
        acc += g;
      }
      sm[8] = acc;
      sm[17] = nt;
      for (int i = nt; i < MAX_TILES; i++) { sm[18 + i] = 0; sm[90 + i] = 0; }
    }
    if (tid < N_EXP) scnt[tid] = 0;
    __syncthreads();
    // prefetch all expert indices first (8 int4 loads in flight), then bucket
    int4 eb[8];
#pragma unroll
    for (int q = 0; q < 8; q++) eb[q] = ((const int4*)eidx)[q * 256 + tid];
#pragma unroll
    for (int q = 0; q < 8; q++) {
      int ii = (q * 256 + tid) * 4;
      const int* ev = (const int*)&eb[q];
#pragma unroll
      for (int j = 0; j < 4; j++) {
        int e = ev[j];
        int p = sm[e] + atomicAdd(&scnt[e], 1);
        row_src[p] = ii + j;
        pos_of[ii + j] = p;
      }
    }
    if (tid < 162) meta[tid] = sm[tid];
  }
}

// ---- grouped GEMM 1: h = silu(x@w1) * (x@w3), bf16 out (NK,H) ----
// 128x64 tile, BK=64, 4 waves of 64x32, dual acc (64 AGPR + 64 VGPR = 128).
// min-waves raised 3->4: 128 regs/thread fits 16 waves/CU, and 1152 jobs
// vs 1024-block capacity cuts the dispatch tail from 1.5 waves to ~1.1.
__global__ __launch_bounds__(256, 4) void gemm_swiglu_kernel(
    const bfbits* __restrict__ xb, const bfbits* __restrict__ w1t,
    const bfbits* __restrict__ w3t, const int* __restrict__ row_src,
    const int* __restrict__ meta, bfbits* __restrict__ hb) {
  int nt = meta[17];
  int bt = blockIdx.y;
  if (bt >= nt) return;
  int e = meta[18 + bt];
  int row0 = meta[90 + bt];
  int rows_end = meta[e + 1];
  int n0 = blockIdx.x * 64;

  __shared__ __align__(16) bfbits As[128 * 64];   // 16 KB
  __shared__ __align__(16) bfbits B1s[64 * 64];   //  8 KB
  __shared__ __align__(16) bfbits B3s[64 * 64];   //  8 KB

  int tid = threadIdx.x, lane = tid & 63, wv = tid >> 6;
  int r8 = lane >> 3, jl = lane & 7;
  int jg = jl ^ r8;   // swizzled global 16B chunk for this lane

  // 32 staging segments of 8 rows each: [0..15]=A, [16..23]=B1, [24..31]=B3
  const bfbits* gp[8]; bfbits* lp[8];
  for (int j = 0; j < 8; j++) {
    int s = wv * 8 + j;
    if (s < 16) {
      int tok = row_src[row0 + s * 8 + r8] >> 1;  // TOPK=2; rows>=rows_end read valid junk, discarded
      gp[j] = xb + (size_t)tok * D_MODEL + jg * 8;
      lp[j] = As + s * 512;
    } else if (s < 24) {
      int b = s - 16;
      gp[j] = w1t + ((size_t)e * H_DIM + n0 + b * 8 + r8) * D_MODEL + jg * 8;
      lp[j] = B1s + b * 512;
    } else {
      int b = s - 24;
      gp[j] = w3t + ((size_t)e * H_DIM + n0 + b * 8 + r8) * D_MODEL + jg * 8;
      lp[j] = B3s + b * 512;
    }
  }

  const f32x4 fzero = {0.f, 0.f, 0.f, 0.f};
  f32x4 accg[4][2], accu[4][2];
  for (int i = 0; i < 4; i++)
    for (int j = 0; j < 2; j++) { accg[i][j] = fzero; accu[i][j] = fzero; }

  int mw = (wv & 1) * 64, nwv = (wv >> 1) * 32;
  int qd = lane >> 4, lr = lane & 15, lr7 = lr & 7;

  for (int kk = 0; kk < D_MODEL / 64; kk++) {
    int ko = kk * 64;
    for (int j = 0; j < 8; j++) glds16(gp[j] + ko, lp[j]);
    __syncthreads();
    for (int ks = 0; ks < 2; ks++) {
      int sb = ((ks * 4 + qd) ^ lr7) << 3;  // swizzled 16B slot in 64-el row
      bf16x8 af[4], b1f[2], b3f[2];
      for (int mi = 0; mi < 4; mi++)
        af[mi] = *(const bf16x8*)&As[(mw + mi * 16 + lr) * 64 + sb];
      for (int ni = 0; ni < 2; ni++) {
        b1f[ni] = *(const bf16x8*)&B1s[(nwv + ni * 16 + lr) * 64 + sb];
        b3f[ni] = *(const bf16x8*)&B3s[(nwv + ni * 16 + lr) * 64 + sb];
      }
      for (int mi = 0; mi < 4; mi++)
        for (int ni = 0; ni < 2; ni++) {
          accg[mi][ni] = __builtin_amdgcn_mfma_f32_16x16x32_bf16(af[mi], b1f[ni], accg[mi][ni], 0, 0, 0);
          accu[mi][ni] = __builtin_amdgcn_mfma_f32_16x16x32_bf16(af[mi], b3f[ni], accu[mi][ni], 0, 0, 0);
        }
    }
    __syncthreads();
  }

  // C/D layout: row=(lane>>4)*4+reg, col=lane&15
  for (int mi = 0; mi < 4; mi++) {
    int rbase = row0 + mw + mi * 16 + qd * 4;
    for (int r = 0; r < 4; r++) {
      int grow = rbase + r;
      if (grow < rows_end) {
        for (int ni = 0; ni < 2; ni++) {
          float gg = accg[mi][ni][r], u = accu[mi][ni][r];
          float h = gg / (1.f + __expf(-gg)) * u;  // silu(g)*u
          hb[(size_t)grow * H_DIM + n0 + nwv + ni * 16 + lr] = f2bf_bits(h);
        }
      }
    }
  }
}

// ---- grouped GEMM 2: out_perm(bf16) = h @ w2 ----
// m97-exact shape: 128x128 tile, BK=64, 256 threads = 4 waves of 64x64,
// acc[4][4] (64 AGPR). 16 MFMA per 8 ds_reads per ks. 32 KB LDS, grid 8x72.
// min-waves 3 (m97 ran 3 blocks/CU at this shape).
__global__ __launch_bounds__(256, 3) void gemm_out_kernel(
    const bfbits* __restrict__ hb, const bfbits* __restrict__ w2t,
    const int* __restrict__ meta, bfbits* __restrict__ out_perm) {
  int nt = meta[17];
  int bt = blockIdx.y;
  if (bt >= nt) return;
  int e = meta[18 + bt];
  int row0 = meta[90 + bt];
  int rows_end = meta[e + 1];
  int n0 = blockIdx.x * 128;

  __shared__ __align__(16) bfbits As[128 * 64];   // 16 KB
  __shared__ __align__(16) bfbits Bs[128 * 64];   // 16 KB

  int tid = threadIdx.x, lane = tid & 63, wv = tid >> 6;
  int r8 = lane >> 3, jl = lane & 7;
  int jg = jl ^ r8;

  // 32 staging segments of 8 rows: [0..15]=A rows (hb, pre-sorted), [16..31]=B rows
  const bfbits* gp[8]; bfbits* lp[8];
  for (int j = 0; j < 8; j++) {
    int s = wv * 8 + j;
    if (s < 16) {
      gp[j] = hb + (size_t)(row0 + s * 8 + r8) * H_DIM + jg * 8;
      lp[j] = As + s * 512;
    } else {
      int b = s - 16;
      gp[j] = w2t + ((size_t)e * D_MODEL + n0 + b * 8 + r8) * H_DIM + jg * 8;
      lp[j] = Bs + b * 512;
    }
  }

  const f32x4 fzero = {0.f, 0.f, 0.f, 0.f};
  f32x4 acc[4][4];
  for (int i = 0; i < 4; i++)
    for (int j = 0; j < 4; j++) acc[i][j] = fzero;

  int mw = (wv & 1) * 64, nw = (wv >> 1) * 64;   // 2x2 wave grid, 64x64 each
  int qd = lane >> 4, lr = lane & 15, lr7 = lr & 7;

  for (int kk = 0; kk < H_DIM / 64; kk++) {
    int ko = kk * 64;
    for (int j = 0; j < 8; j++) glds16(gp[j] + ko, lp[j]);
    __syncthreads();
    for (int ks = 0; ks < 2; ks++) {
      int sb = ((ks * 4 + qd) ^ lr7) << 3;
      bf16x8 af[4], bfr[4];
      for (int mi = 0; mi < 4; mi++)
        af[mi] = *(const bf16x8*)&As[(mw + mi * 16 + lr) * 64 + sb];
      for (int ni = 0; ni < 4; ni++)
        bfr[ni] = *(const bf16x8*)&Bs[(nw + ni * 16 + lr) * 64 + sb];
      for (int mi = 0; mi < 4; mi++)
        for (int ni = 0; ni < 4; ni++)
          acc[mi][ni] = __builtin_amdgcn_mfma_f32_16x16x32_bf16(af[mi], bfr[ni], acc[mi][ni], 0, 0, 0);
    }
    __syncthreads();
  }

  for (int mi = 0; mi < 4; mi++) {
    int rbase = row0 + mw + mi * 16 + qd * 4;
    for (int r = 0; r < 4; r++) {
      int grow = rbase + r;
      if (grow < rows_end) {
        for (int ni = 0; ni < 4; ni++)
          out_perm[(size_t)grow * D_MODEL + n0 + nw + ni * 16 + lr] = f2bf_bits(acc[mi][ni][r]);
      }
    }
  }
}

// ---- weighted combine of the two copies per token (bf16 in, fp32 out) ----
// 4 float4 per thread; within an iteration all threads share one token ->
// pos_of/ew loads are wave-uniform (scalar).
__global__ __launch_bounds__(256) void combine_kernel(
    const ushort4* __restrict__ out_perm, const int* __restrict__ pos_of,
    const float* __restrict__ ew, float4* __restrict__ out) {
  int tid = threadIdx.x;
#pragma unroll
  for (int q = 0; q < 4; q++) {
    int i = blockIdx.x * 1024 + q * 256 + tid;  // over N_TOK * D/4
    int tok = i >> 8;                            // D/4 = 256
    int col = i & 255;
    int p0 = pos_of[2 * tok], p1 = pos_of[2 * tok + 1];
    float w0 = ew[2 * tok], w1 = ew[2 * tok + 1];
    ushort4 a = out_perm[(size_t)p0 * 256 + col];
    ushort4 b = out_perm[(size_t)p1 * 256 + col];
    float4 o;
    o.x = w0 * bf2f(a.x) + w1 * bf2f(b.x);
    o.y = w0 * bf2f(a.y) + w1 * bf2f(b.y);
    o.z = w0 * bf2f(a.z) + w1 * bf2f(b.z);
    o.w = w0 * bf2f(a.w) + w1 * bf2f(b.w);
    out[i] = o;
  }
}

extern "C" void kernel_launch(void* const* d_in, const int* in_sizes, int n_in,
                              void* d_out, int out_size, void* d_ws, size_t ws_size,
                              hipStream_t stream) {
  const float* x  = (const float*)d_in[0];
  const float* ew = (const float*)d_in[1];
  const int* eidx = (const int*)d_in[2];
  const int* bspe = (const int*)d_in[3];
  const float* w1 = (const float*)d_in[4];
  const float* w2 = (const float*)d_in[5];
  const float* w3 = (const float*)d_in[6];
  float* out = (float*)d_out;

  char* ws = (char*)d_ws;
  const size_t MB = 1024 * 1024;
  bfbits* w1t   = (bfbits*)(ws);             // 16 MB (E,H,D)
  bfbits* w3t   = (bfbits*)(ws + 16 * MB);   // 16 MB (E,H,D)
  bfbits* w2t   = (bfbits*)(ws + 32 * MB);   // 16 MB (E,D,H)
  bfbits* xb    = (bfbits*)(ws + 48 * MB);   //  8 MB (N,D)
  bfbits* hb    = (bfbits*)(ws + 56 * MB);   // 16 MB (NK,H)
  // out_perm (16 MB bf16) aliases w1t — dead after gemm_swiglu completes
  bfbits* out_perm = (bfbits*)(ws);
  int* row_src  = (int*)(ws + 72 * MB);              // 32 KB
  int* pos_of   = (int*)(ws + 72 * MB + 32 * 1024);  // 32 KB
  int* meta     = (int*)(ws + 72 * MB + 64 * 1024);

  prepass_kernel<<<dim3(16, 8, 33), 256, 0, stream>>>(
      x, eidx, bspe, w1, w2, w3, w1t, w2t, w3t, xb, meta, row_src, pos_of);
  gemm_swiglu_kernel<<<dim3(H_DIM / 64, MAX_TILES), 256, 0, stream>>>(
      xb, w1t, w3t, row_src, meta, hb);
  gemm_out_kernel<<<dim3(D_MODEL / 128, MAX_TILES), 256, 0, stream>>>(
      hb, w2t, meta, out_perm);
  combine_kernel<<<(N_TOK * D_MODEL / 4) / 1024, 256, 0, stream>>>(
      (const ushort4*)out_perm, pos_of, ew, (float4*)out);
}